// Round 8
// baseline (390.482 us; speedup 1.0000x reference)
//
#include <hip/hip_runtime.h>
#include <hip/hip_bf16.h>

typedef __hip_bfloat16 bf16;
typedef __attribute__((ext_vector_type(8))) __bf16 bf16x8;
typedef __attribute__((ext_vector_type(4))) float f32x4;

__device__ __forceinline__ float toF(bf16 v) { return __bfloat162float(v); }

// dual-dtype load: dt=1 -> underlying memory is fp32; dt=0 -> bf16
__device__ __forceinline__ float ldf(const void* p, size_t i, int dt) {
  return dt ? ((const float*)p)[i] : __bfloat162float(((const bf16*)p)[i]);
}
__device__ __forceinline__ ushort toBF(float f) {
  union { bf16 b; ushort u; } cv; cv.b = __float2bfloat16(f); return cv.u;
}

// block-local dtype detection (deterministic across blocks: same data, same rule).
// Lets pack blocks run in the SAME dispatch as the flag-writing block.
__device__ __forceinline__ int block_detect(const void* x, int ndet) {
  __shared__ int sdet;
  if (threadIdx.x == 0) sdet = 0;
  __syncthreads();
  const bf16* xb = (const bf16*)x;
  int bad = 0;
  for (int i = threadIdx.x; i < ndet; i += 256) {
    float v = __bfloat162float(xb[i]);
    if (!(fabsf(v) < 1e6f)) bad = 1;
  }
  if (bad) atomicOr(&sdet, 1);
  __syncthreads();
  return sdet;
}

// ---------------- fused dispatch #1: zero cnt | pack Wt0/Wt1/HW | write flag ----------
// Block roles by blockIdx (launch overhead ~10us/dispatch dominates the pipeline;
// this merges 4 round-7 dispatches into 1).
// Wt2 layout for direct MFMA frag loads: Wt2[k/8][col][k%8], zero-padded k in [K,Kpad).
__global__ __launch_bounds__(256) void fused_init_pack(
    const void* __restrict__ x, int ndet, int* __restrict__ flag,
    int* __restrict__ cnt, int N,
    const void* __restrict__ W0, const void* __restrict__ W1,
    const void* __restrict__ Wn, const void* __restrict__ Wr,
    const void* __restrict__ bn, const void* __restrict__ br,
    const void* __restrict__ Wc, const void* __restrict__ bc,
    ushort* __restrict__ Wt0, ushort* __restrict__ Wt1, float* __restrict__ HW,
    int IN, int Kpad0, int nz, int hb) {
  int b = blockIdx.x, t = threadIdx.x;
  if (b < nz) {
    int i = b * 256 + t;
    if (i < N) cnt[i] = 0;
  } else if (b < nz + 128) {
    int dt = block_detect(x, ndet);
    int c = b - nz;                       // Wt0 column, K=IN padded to Kpad0
    for (int k = t; k < Kpad0; k += 256) {
      float v = (k < IN) ? ldf(W0, (size_t)k * 128 + c, dt) : 0.f;
      Wt0[((size_t)(k >> 3) * 128 + c) * 8 + (k & 7)] = toBF(v);
    }
  } else if (b < nz + 256) {
    int dt = block_detect(x, ndet);
    int c = b - nz - 128;                 // Wt1 column, K=128
    if (t < 128) {
      int k = t;
      Wt1[((size_t)(k >> 3) * 128 + c) * 8 + (k & 7)] = toBF(ldf(W1, (size_t)k * 128 + c, dt));
    }
  } else if (b < nz + 256 + hb) {
    int dt = block_detect(x, ndet);
    int i = (b - nz - 256) * 256 + t;     // head fp32 pack: [Wn | Wr | bn | br | Wc | bc]
    int s0 = IN * 128, s1 = s0 + 128 * 128, s2 = s1 + 128, s3 = s2 + 128, s4 = s3 + 256, s5 = s4 + 1;
    if (i >= s5) return;
    float v;
    if (i < s0) v = ldf(Wn, i, dt);
    else if (i < s1) v = ldf(Wr, i - s0, dt);
    else if (i < s2) v = ldf(bn, i - s1, dt);
    else if (i < s3) v = ldf(br, i - s2, dt);
    else if (i < s4) v = ldf(Wc, i - s3, dt);
    else v = ldf(bc, 0, dt);
    HW[i] = v;
  } else {
    int dt = block_detect(x, ndet);       // global flag for later dispatches
    if (t == 0) flag[0] = dt;
  }
}

// ---------------- CSR build ----------------
__global__ void count_rank(const int* __restrict__ ei, int E,
                           int* __restrict__ cnt, int* __restrict__ rank) {
  int e = blockIdx.x * blockDim.x + threadIdx.x;
  if (e >= E) return;
  int d = ei[E + e];
  rank[e] = atomicAdd(&cnt[d], 1);
}

// single-block exclusive scan of cnt[0..n) -> rowstart (replaces 3-kernel scan chain).
// 1024 threads x contiguous segments; LDS Hillis-Steele over segment sums.
__global__ __launch_bounds__(1024) void scan_block(const int* __restrict__ cnt, int n,
                                                   int* __restrict__ rowstart) {
  __shared__ int sums[1024];
  int t = threadIdx.x;
  int L = (n + 1023) >> 10;
  int lo = t * L;
  int hi = lo + L < n ? lo + L : n;
  int s = 0;
  for (int i = lo; i < hi; i++) s += cnt[i];
  sums[t] = s;
  for (int off = 1; off < 1024; off <<= 1) {
    __syncthreads();
    int v = (t >= off) ? sums[t - off] : 0;
    __syncthreads();
    sums[t] += v;
  }
  __syncthreads();
  int run = sums[t] - s;                  // exclusive prefix at segment start
  for (int i = lo; i < hi; i++) { rowstart[i] = run; run += cnt[i]; }
  if (t == 1023) rowstart[n] = sums[1023];
}

__global__ void scatter2(const int* __restrict__ ei, int E,
                         const int* __restrict__ rowstart, const int* __restrict__ rank,
                         int* __restrict__ adj) {
  int e = blockIdx.x * blockDim.x + threadIdx.x;
  if (e >= E) return;
  int s = ei[e], d = ei[E + e];
  adj[rowstart[d] + rank[e]] = s;
}

// ---------------- MFMA GEMM v4: LDS A-panel, fused fp32->bf16 staging ----------------
// C[nrows,128] = A[nrows,K] @ W[K,128]. LDS panel rows are bf16, RB bytes each.
// CVT=true: when dtflag says fp32, stage-convert from fp32 source directly.
// One barrier; K-loop reads A-frags from LDS, W frags from global (L2-resident).
template <int RB, bool ALIGN16, bool CVT>
__global__ __launch_bounds__(256) void mfma_gemm4(const void* __restrict__ A0,
                                                  const ushort* __restrict__ Wt2,
                                                  bf16* __restrict__ C,
                                                  float2* __restrict__ as2, float2* __restrict__ ad2,
                                                  const void* __restrict__ aS, const void* __restrict__ aD,
                                                  int nrows, int K, const int* __restrict__ dtflag) {
  __shared__ __align__(16) unsigned char panel[64 * RB + 64];  // +64 pad (zeroed) for tail reads
  int dtg = dtflag[0];
  int tid = threadIdx.x;
  int row0 = blockIdx.x * 64;

  if (CVT && dtg) {
    const float* Af = (const float*)A0 + (size_t)row0 * K;
    size_t availf = (size_t)nrows * K - (size_t)row0 * K;
    size_t pf = availf < (size_t)(64 * K) ? availf : (size_t)(64 * K);
    int nch = (int)(pf >> 2);
    for (int c = tid; c < nch; c += 256) {
      float4 v = ((const float4*)Af)[c];
      uint2 o;
      o.x = (uint)toBF(v.x) | ((uint)toBF(v.y) << 16);
      o.y = (uint)toBF(v.z) | ((uint)toBF(v.w) << 16);
      *(uint2*)&panel[(size_t)c << 3] = o;
    }
    for (int f = (nch << 2) + tid; f < (int)pf; f += 256)
      ((ushort*)panel)[f] = toBF(Af[f]);
    for (int u2 = (int)pf + tid; u2 < (64 * RB + 64) / 2; u2 += 256)
      ((ushort*)panel)[u2] = 0;
  } else {
    const unsigned char* A = (const unsigned char*)A0;
    size_t gbase = (size_t)row0 * RB;
    size_t avail = (size_t)nrows * RB - gbase;
    size_t pbytes = avail < (size_t)(64 * RB) ? avail : (size_t)(64 * RB);
    int nchunk = (int)(pbytes >> 4);
    const uint4* gsrc = (const uint4*)(A + gbase);
    for (int c = tid; c < nchunk; c += 256)
      *(uint4*)&panel[(size_t)c << 4] = gsrc[c];
    for (int b = (nchunk << 4) + tid * 4; b < (int)pbytes; b += 1024)
      *(uint*)&panel[b] = *(const uint*)(A + gbase + b);
    for (int b = (int)((pbytes + 3) & ~3ull) + tid * 4; b < 64 * RB + 64; b += 1024)
      *(uint*)&panel[b] = 0u;
  }
  __syncthreads();

  int wave = tid >> 6, lane = tid & 63;
  int m = lane & 15, q = lane >> 4;
  int lrow = wave * 16 + m;
  const unsigned char* prow = &panel[(size_t)lrow * RB];

  f32x4 acc[8];
#pragma unroll
  for (int ct = 0; ct < 8; ct++) acc[ct] = (f32x4){0.f, 0.f, 0.f, 0.f};

  const ushort* wq = Wt2 + (size_t)q * 1024 + (size_t)m * 8;
  int niter = (K + 31) >> 5;
  for (int it = 0; it < niter; it++) {
    bf16x8 av;
    if (ALIGN16) {
      av = *(const bf16x8*)(prow + it * 64 + q * 16);
    } else {
      uint u[4];
#pragma unroll
      for (int j = 0; j < 4; j++) u[j] = *(const uint*)(prow + it * 64 + q * 16 + j * 4);
      __builtin_memcpy(&av, u, 16);
    }
    const ushort* wk = wq + (size_t)it * 4096;
    bf16x8 wv[8];
#pragma unroll
    for (int ct = 0; ct < 8; ct++) wv[ct] = *(const bf16x8*)(wk + ct * 128);
#pragma unroll
    for (int ct = 0; ct < 8; ct++)
      acc[ct] = __builtin_amdgcn_mfma_f32_16x16x32_bf16(av, wv[ct], acc[ct], 0, 0, 0);
  }

  // ---- C writeback (C/D: col=lane&15, row=q*4+r) ----
#pragma unroll
  for (int ct = 0; ct < 8; ct++) {
#pragma unroll
    for (int r = 0; r < 4; r++) {
      int grow = row0 + wave * 16 + q * 4 + r;
      if (grow < nrows) C[(size_t)grow * 128 + ct * 16 + m] = __float2bfloat16(acc[ct][r]);
    }
  }

  // ---- fused attention logits ----
  float aSv[8], aDv[8];
#pragma unroll
  for (int ct = 0; ct < 8; ct++) {
    aSv[ct] = ldf(aS, ct * 16 + m, dtg);
    aDv[ct] = ldf(aD, ct * 16 + m, dtg);
  }
#pragma unroll
  for (int r = 0; r < 4; r++) {
    float s0 = 0.f, s1 = 0.f, d0 = 0.f, d1 = 0.f;
#pragma unroll
    for (int ct = 0; ct < 4; ct++) {
      float v = acc[ct][r];
      s0 += v * aSv[ct]; d0 += v * aDv[ct];
    }
#pragma unroll
    for (int ct = 4; ct < 8; ct++) {
      float v = acc[ct][r];
      s1 += v * aSv[ct]; d1 += v * aDv[ct];
    }
#pragma unroll
    for (int off = 1; off < 16; off <<= 1) {
      s0 += __shfl_xor(s0, off, 64);
      s1 += __shfl_xor(s1, off, 64);
      d0 += __shfl_xor(d0, off, 64);
      d1 += __shfl_xor(d1, off, 64);
    }
    int grow = row0 + wave * 16 + q * 4 + r;
    if (m == 0 && grow < nrows) {
      as2[grow] = make_float2(s0, s1);
      ad2[grow] = make_float2(d0, d1);
    }
  }
}

// ---------------- generic fallback GEMM (any K / dtype) -------
__global__ __launch_bounds__(256) void mfma_gemm_gen(const void* __restrict__ A, const ushort* __restrict__ Wt2,
                                                     bf16* __restrict__ C,
                                                     float2* __restrict__ as2, float2* __restrict__ ad2,
                                                     const void* __restrict__ aS, const void* __restrict__ aD,
                                                     int nrows, int K, const int* __restrict__ dtflag) {
  int dtg = dtflag[0];
  int tid = threadIdx.x;
  int wave = tid >> 6, lane = tid & 63;
  int m = lane & 15, q = lane >> 4;
  int row0 = blockIdx.x * 64;
  int rowA = row0 + wave * 16 + m;
  int rA = rowA < nrows ? rowA : nrows - 1;

  f32x4 acc[8];
#pragma unroll
  for (int ct = 0; ct < 8; ct++) acc[ct] = (f32x4){0.f, 0.f, 0.f, 0.f};

  const ushort* wq = Wt2 + (size_t)q * 1024 + (size_t)m * 8;
  int niter = (K + 31) >> 5;
  for (int it = 0; it < niter; it++) {
    ushort u[8];
#pragma unroll
    for (int j = 0; j < 8; j++) {
      int k = it * 32 + q * 8 + j;
      u[j] = (k < K) ? toBF(ldf(A, (size_t)rA * K + k, dtg)) : (ushort)0;
    }
    bf16x8 av;
    __builtin_memcpy(&av, u, 16);
    const ushort* wk = wq + (size_t)it * 4096;
    bf16x8 wv[8];
#pragma unroll
    for (int ct = 0; ct < 8; ct++) wv[ct] = *(const bf16x8*)(wk + ct * 128);
#pragma unroll
    for (int ct = 0; ct < 8; ct++)
      acc[ct] = __builtin_amdgcn_mfma_f32_16x16x32_bf16(av, wv[ct], acc[ct], 0, 0, 0);
  }
#pragma unroll
  for (int ct = 0; ct < 8; ct++) {
#pragma unroll
    for (int r = 0; r < 4; r++) {
      int grow = row0 + wave * 16 + q * 4 + r;
      if (grow < nrows) C[(size_t)grow * 128 + ct * 16 + m] = __float2bfloat16(acc[ct][r]);
    }
  }
  float aSv[8], aDv[8];
#pragma unroll
  for (int ct = 0; ct < 8; ct++) {
    aSv[ct] = ldf(aS, ct * 16 + m, dtg);
    aDv[ct] = ldf(aD, ct * 16 + m, dtg);
  }
#pragma unroll
  for (int r = 0; r < 4; r++) {
    float s0 = 0.f, s1 = 0.f, d0 = 0.f, d1 = 0.f;
#pragma unroll
    for (int ct = 0; ct < 4; ct++) { float v = acc[ct][r]; s0 += v * aSv[ct]; d0 += v * aDv[ct]; }
#pragma unroll
    for (int ct = 4; ct < 8; ct++) { float v = acc[ct][r]; s1 += v * aSv[ct]; d1 += v * aDv[ct]; }
#pragma unroll
    for (int off = 1; off < 16; off <<= 1) {
      s0 += __shfl_xor(s0, off, 64);
      s1 += __shfl_xor(s1, off, 64);
      d0 += __shfl_xor(d0, off, 64);
      d1 += __shfl_xor(d1, off, 64);
    }
    int grow = row0 + wave * 16 + q * 4 + r;
    if (m == 0 && grow < nrows) {
      as2[grow] = make_float2(s0, s1);
      ad2[grow] = make_float2(d0, d1);
    }
  }
}

// ---------------- GAT aggregate, write epilogue (round-1 proven structure) ----------
// One wave per node; per-edge weights cached in wave-private LDS slot; den reduced
// BEFORE the gather loop; 8-deep batched gathers; barrier-free. Writes bf16 h row.
// (Round-6 A/B: per-node atomic pooling costs ~80us -> pooling lives in the head now.)
#define GCAP 64
__global__ __launch_bounds__(256) void gat_agg7w(const bf16* __restrict__ xw,
                                                 const float2* __restrict__ as2, const float2* __restrict__ ad2,
                                                 const int* __restrict__ rowstart, const int* __restrict__ adj,
                                                 const void* __restrict__ bias, bf16* __restrict__ out, int N,
                                                 const int* __restrict__ dtflag) {
  __shared__ float2 sW[4][GCAP];
  __shared__ int sS[4][GCAP];
  int dt = dtflag[0];
  int wslot = threadIdx.x >> 6;
  int lane = threadIdx.x & 63;
  int n = (blockIdx.x * blockDim.x + threadIdx.x) >> 6;
  bool act = n < N;
  int r0 = 0, r1 = 0;
  float2 adv = make_float2(0.f, 0.f), asn = make_float2(0.f, 0.f);
  if (act) { r0 = rowstart[n]; r1 = rowstart[n + 1]; adv = ad2[n]; asn = as2[n]; }
  int deg = r1 - r0;

  float es0 = asn.x + adv.x; es0 = es0 > 0.f ? es0 : 0.2f * es0;
  float es1 = asn.y + adv.y; es1 = es1 > 0.f ? es1 : 0.2f * es1;
  float ws0 = __expf(fminf(es0, 60.f)), ws1 = __expf(fminf(es1, 60.f));

  float den0, den1;
  {
    bool v = act && lane < deg;
    int s = v ? adj[r0 + lane] : 0;
    float w0 = 0.f, w1 = 0.f;
    if (v) {
      float2 asv = as2[s];
      float e0 = asv.x + adv.x; e0 = e0 > 0.f ? e0 : 0.2f * e0;
      float e1 = asv.y + adv.y; e1 = e1 > 0.f ? e1 : 0.2f * e1;
      w0 = __expf(fminf(e0, 60.f)); w1 = __expf(fminf(e1, 60.f));
    }
    sW[wslot][lane] = make_float2(w0, w1);
    sS[wslot][lane] = s;
    den0 = w0; den1 = w1;
  }
  for (int i = r0 + GCAP + lane; i < r1; i += 64) {
    int s = adj[i];
    float2 asv = as2[s];
    float e0 = asv.x + adv.x; e0 = e0 > 0.f ? e0 : 0.2f * e0;
    float e1 = asv.y + adv.y; e1 = e1 > 0.f ? e1 : 0.2f * e1;
    den0 += __expf(fminf(e0, 60.f)); den1 += __expf(fminf(e1, 60.f));
  }
#pragma unroll
  for (int off = 32; off > 0; off >>= 1) {
    den0 += __shfl_xor(den0, off, 64);
    den1 += __shfl_xor(den1, off, 64);
  }
  den0 += ws0; den1 += ws1;
  float inv0 = 1.f / (den0 + 1e-16f), inv1 = 1.f / (den1 + 1e-16f);

  const uint* xw32 = (const uint*)xw;
  float wsS = (lane < 32) ? ws0 : ws1;
  uint pvs = act ? xw32[((size_t)n << 6) + lane] : 0;
  float a0 = wsS * __uint_as_float(pvs << 16);
  float a1 = wsS * __uint_as_float(pvs & 0xffff0000u);
  int cap = deg < GCAP ? deg : GCAP;
  int capR = (cap + 7) & ~7;   // wave-uniform; slots [cap,capR) have w=0,s=0
  for (int i = 0; i < capR; i += 8) {
    uint pv[8]; float wsv[8];
#pragma unroll
    for (int j = 0; j < 8; j++) {
      float2 wv = sW[wslot][i + j];
      int s = sS[wslot][i + j];
      wsv[j] = (lane < 32) ? wv.x : wv.y;
      pv[j] = xw32[((size_t)s << 6) + lane];
    }
#pragma unroll
    for (int j = 0; j < 8; j++) {
      a0 += wsv[j] * __uint_as_float(pv[j] << 16);
      a1 += wsv[j] * __uint_as_float(pv[j] & 0xffff0000u);
    }
  }
  for (int i = GCAP; i < deg; i++) {
    int s = adj[r0 + i];
    float2 asv = as2[s];
    float e0 = asv.x + adv.x; e0 = e0 > 0.f ? e0 : 0.2f * e0;
    float e1 = asv.y + adv.y; e1 = e1 > 0.f ? e1 : 0.2f * e1;
    float w0 = __expf(fminf(e0, 60.f)), w1 = __expf(fminf(e1, 60.f));
    uint pv = xw32[((size_t)s << 6) + lane];
    float ws = (lane < 32) ? w0 : w1;
    a0 += ws * __uint_as_float(pv << 16);
    a1 += ws * __uint_as_float(pv & 0xffff0000u);
  }
  if (act) {
    int c0 = 2 * lane;
    float invs = (lane < 32) ? inv0 : inv1;
    float o0 = a0 * invs + ldf(bias, c0, dt);
    float o1 = a1 * invs + ldf(bias, c0 + 1, dt);
    o0 = o0 > 0.f ? o0 : 0.f;
    o1 = o1 > 0.f ? o1 : 0.f;
    uint pk = (uint)toBF(o0) | ((uint)toBF(o1) << 16);
    ((uint*)out)[(size_t)n * 64 + lane] = pk;
  }
}

// ---------------- head v5: mean-pool fused in (no pool dispatch, no atomics) ----------
// Each block owns graph b; binary-search gives [r0,r1); the 4 thread-groups sum
// h rows r0+g, r0+g+4, ... into pn scratch, reduce to pl, then the head matmuls.
__global__ __launch_bounds__(512) void head5_kernel(
    const bf16* __restrict__ h, const void* __restrict__ x, const int* __restrict__ batch,
    const float* __restrict__ HW, void* __restrict__ out, int N, int IN,
    const int* __restrict__ dtflag) {
  const float* Wn_f = HW;
  const float* Wr_f = HW + (size_t)IN * 128;
  const float* bn_f = Wr_f + 128 * 128;
  const float* br_f = bn_f + 128;
  const float* Wc_f = br_f + 128;
  const float* bc_f = Wc_f + 256;
  int dt = dtflag[0];
  int b = blockIdx.x;
  int tid = threadIdx.x;
  int t = tid & 127, g = tid >> 7;
  __shared__ int sr0, sr1;
  __shared__ float xs[512];
  __shared__ float pl[128];
  __shared__ float pn[4][128];
  __shared__ float pg[4][128];
  __shared__ float red[128];
  if (tid == 0) {
    int lo = 0, hi = N;
    while (lo < hi) { int mid = (lo + hi) >> 1; if (batch[mid] < b) lo = mid + 1; else hi = mid; }
    sr0 = lo;
  }
  if (tid == 1) {
    int lo = 0, hi = N, b1 = b + 1;
    while (lo < hi) { int mid = (lo + hi) >> 1; if (batch[mid] < b1) lo = mid + 1; else hi = mid; }
    sr1 = lo;
  }
  __syncthreads();
  int r0 = sr0, r1 = sr1;
  float inv_cnt = 1.f / (float)(r1 - r0);
  // root-node features into xs (independent of pool)
  if (dt) {
    const float* xf = (const float*)x + (size_t)r0 * IN;
    for (int k = tid; k < IN; k += 512) xs[k] = xf[k];
  } else {
    const bf16* xb = (const bf16*)x + (size_t)r0 * IN;
    for (int k = tid; k < IN; k += 512) xs[k] = toF(xb[k]);
  }
  // inline mean-pool over this graph's h rows (pn as scratch)
  float ap = 0.f;
  for (int nr = r0 + g; nr < r1; nr += 4)
    ap += toF(h[(size_t)nr * 128 + t]);
  pn[g][t] = ap;
  __syncthreads();
  if (tid < 128) pl[tid] = (pn[0][tid] + pn[1][tid] + pn[2][tid] + pn[3][tid]) * inv_cnt;
  __syncthreads();

  float n0 = 0.f, n1 = 0.f, n2 = 0.f, n3 = 0.f;
  {
    int k = g;
    for (; k + 12 < IN; k += 16) {
      n0 += xs[k]      * Wn_f[(size_t)k * 128 + t];
      n1 += xs[k + 4]  * Wn_f[(size_t)(k + 4) * 128 + t];
      n2 += xs[k + 8]  * Wn_f[(size_t)(k + 8) * 128 + t];
      n3 += xs[k + 12] * Wn_f[(size_t)(k + 12) * 128 + t];
    }
    for (; k < IN; k += 4) n0 += xs[k] * Wn_f[(size_t)k * 128 + t];
  }
  float g0 = 0.f, g1 = 0.f;
  {
    int k = g;
    for (; k + 4 < 128; k += 8) {
      g0 += pl[k]     * Wr_f[(size_t)k * 128 + t];
      g1 += pl[k + 4] * Wr_f[(size_t)(k + 4) * 128 + t];
    }
    for (; k < 128; k += 4) g0 += pl[k] * Wr_f[(size_t)k * 128 + t];
  }
  pn[g][t] = (n0 + n1) + (n2 + n3);
  pg[g][t] = g0 + g1;
  __syncthreads();
  if (tid < 128) {
    float nw = pn[0][t] + pn[1][t] + pn[2][t] + pn[3][t] + bn_f[t];
    nw = nw > 0.f ? nw : 0.f;
    float gg = pg[0][t] + pg[1][t] + pg[2][t] + pg[3][t] + br_f[t];
    gg = gg > 0.f ? gg : 0.f;
    red[t] = gg * Wc_f[t] + nw * Wc_f[128 + t];
  }
  __syncthreads();
  for (int s = 64; s > 0; s >>= 1) {
    if (tid < s) red[tid] += red[tid + s];
    __syncthreads();
  }
  if (tid == 0) {
    float z = red[0] + bc_f[0];
    float r = 1.f / (1.f + __expf(-z));
    if (dt) ((float*)out)[b] = r;
    else ((bf16*)out)[b] = __float2bfloat16(r);
  }
}

extern "C" void kernel_launch(void* const* d_in, const int* in_sizes, int n_in,
                              void* d_out, int out_size, void* d_ws, size_t ws_size,
                              hipStream_t stream) {
  const void* x   = d_in[0];
  const void* W0  = d_in[1];
  const void* aS0 = d_in[2];
  const void* aD0 = d_in[3];
  const void* b0  = d_in[4];
  const void* W1  = d_in[5];
  const void* aS1 = d_in[6];
  const void* aD1 = d_in[7];
  const void* b1  = d_in[8];
  const void* Wn  = d_in[9];
  const void* bn  = d_in[10];
  const void* Wr  = d_in[11];
  const void* br  = d_in[12];
  const void* Wc  = d_in[13];
  const void* bc  = d_in[14];
  const int* ei    = (const int*)d_in[15];
  const int* batch = (const int*)d_in[16];

  const int N = in_sizes[16];
  const int IN = in_sizes[0] / N;
  const int E = in_sizes[15] / 2;
  const int B = out_size;
  const int Kpad0 = (IN + 31) / 32 * 32;   // 320
  const int hw_elems = IN * 128 + 128 * 128 + 128 + 128 + 256 + 1;

  char* w = (char*)d_ws;
  size_t off = 0;
  auto alloc = [&](size_t bytes) { void* p = w + off; off += (bytes + 255) / 256 * 256; return p; };
  int* flag      = (int*)alloc(256);
  bf16* bufA     = (bf16*)alloc((size_t)N * 128 * 2);
  bf16* bufB     = (bf16*)alloc((size_t)N * 128 * 2);
  float2* as2    = (float2*)alloc((size_t)N * 8);
  float2* ad2    = (float2*)alloc((size_t)N * 8);
  int* cnt       = (int*)alloc((size_t)N * 4);
  int* rowstart  = (int*)alloc((size_t)(N + 1) * 4);
  int* rank      = (int*)alloc((size_t)E * 4);
  int* adj       = (int*)alloc((size_t)E * 4);
  ushort* Wt0    = (ushort*)alloc((size_t)128 * Kpad0 * 2);
  ushort* Wt1    = (ushort*)alloc((size_t)128 * 128 * 2);
  float* HW      = (float*)alloc((size_t)hw_elems * 4);

  int ndet = in_sizes[0] < 4096 ? in_sizes[0] : 4096;
  int nz = (N + 255) / 256;
  int hb = (hw_elems + 255) / 256;
  int fgrid = nz + 256 + hb + 1;

  // dispatch 1: zero cnt + pack Wt0/Wt1/HW (self-detect) + write dtype flag
  fused_init_pack<<<fgrid, 256, 0, stream>>>(x, ndet, flag, cnt, N,
                                             W0, W1, Wn, Wr, bn, br, Wc, bc,
                                             Wt0, Wt1, HW, IN, Kpad0, nz, hb);

  // dispatches 2-4: CSR build (count -> single-block scan -> scatter)
  const int tb = 256;
  count_rank<<<(E + tb - 1) / tb, tb, 0, stream>>>(ei, E, cnt, rank);
  scan_block<<<1, 1024, 0, stream>>>(cnt, N, rowstart);
  scatter2<<<(E + tb - 1) / tb, tb, 0, stream>>>(ei, E, rowstart, rank, adj);

  int ggrid = (N + 63) / 64;
  int wgrid = ((N * 64) + 255) / 256;

  // dispatches 5-8: layer 0 (GEMM + aggregate), layer 1 (GEMM + aggregate)
  if (IN == 310) {
    mfma_gemm4<620, false, true><<<ggrid, 256, 0, stream>>>(x, Wt0, bufA, as2, ad2, aS0, aD0, N, IN, flag);
  } else {
    mfma_gemm_gen<<<ggrid, 256, 0, stream>>>(x, Wt0, bufA, as2, ad2, aS0, aD0, N, IN, flag);
  }
  gat_agg7w<<<wgrid, 256, 0, stream>>>(bufA, as2, ad2, rowstart, adj, b0, bufB, N, flag);

  mfma_gemm4<256, true, false><<<ggrid, 256, 0, stream>>>(bufB, Wt1, bufA, as2, ad2, aS1, aD1, N, 128, flag);
  gat_agg7w<<<wgrid, 256, 0, stream>>>(bufA, as2, ad2, rowstart, adj, b1, bufB, N, flag);

  // dispatch 9: head with fused mean-pool
  head5_kernel<<<B, 512, 0, stream>>>(bufB, x, batch, HW, (void*)d_out, N, IN, flag);
}

// Round 9
// 320.168 us; speedup vs baseline: 1.2196x; 1.2196x over previous
//
#include <hip/hip_runtime.h>
#include <hip/hip_bf16.h>

typedef __hip_bfloat16 bf16;
typedef __attribute__((ext_vector_type(8))) __bf16 bf16x8;
typedef __attribute__((ext_vector_type(4))) float f32x4;

__device__ __forceinline__ float toF(bf16 v) { return __bfloat162float(v); }

// dual-dtype load: dt=1 -> underlying memory is fp32; dt=0 -> bf16
__device__ __forceinline__ float ldf(const void* p, size_t i, int dt) {
  return dt ? ((const float*)p)[i] : __bfloat162float(((const bf16*)p)[i]);
}
__device__ __forceinline__ ushort toBF(float f) {
  union { bf16 b; ushort u; } cv; cv.b = __float2bfloat16(f); return cv.u;
}

// block-local dtype detection (deterministic across blocks: same data, same rule).
__device__ __forceinline__ int block_detect(const void* x, int ndet) {
  __shared__ int sdet;
  if (threadIdx.x == 0) sdet = 0;
  __syncthreads();
  const bf16* xb = (const bf16*)x;
  int bad = 0;
  for (int i = threadIdx.x; i < ndet; i += 256) {
    float v = __bfloat162float(xb[i]);
    if (!(fabsf(v) < 1e6f)) bad = 1;
  }
  if (bad) atomicOr(&sdet, 1);
  __syncthreads();
  return sdet;
}

// ---------------- fused dispatch #1: zero cnt | pack Wt0/Wt1/HW | write flag ----------
__global__ __launch_bounds__(256) void fused_init_pack(
    const void* __restrict__ x, int ndet, int* __restrict__ flag,
    int* __restrict__ cnt, int N,
    const void* __restrict__ W0, const void* __restrict__ W1,
    const void* __restrict__ Wn, const void* __restrict__ Wr,
    const void* __restrict__ bn, const void* __restrict__ br,
    const void* __restrict__ Wc, const void* __restrict__ bc,
    ushort* __restrict__ Wt0, ushort* __restrict__ Wt1, float* __restrict__ HW,
    int IN, int Kpad0, int nz, int hb) {
  int b = blockIdx.x, t = threadIdx.x;
  if (b < nz) {
    int i = b * 256 + t;
    if (i < N) cnt[i] = 0;
  } else if (b < nz + 128) {
    int dt = block_detect(x, ndet);
    int c = b - nz;                       // Wt0 column, K=IN padded to Kpad0
    for (int k = t; k < Kpad0; k += 256) {
      float v = (k < IN) ? ldf(W0, (size_t)k * 128 + c, dt) : 0.f;
      Wt0[((size_t)(k >> 3) * 128 + c) * 8 + (k & 7)] = toBF(v);
    }
  } else if (b < nz + 256) {
    int dt = block_detect(x, ndet);
    int c = b - nz - 128;                 // Wt1 column, K=128
    if (t < 128) {
      int k = t;
      Wt1[((size_t)(k >> 3) * 128 + c) * 8 + (k & 7)] = toBF(ldf(W1, (size_t)k * 128 + c, dt));
    }
  } else if (b < nz + 256 + hb) {
    int dt = block_detect(x, ndet);
    int i = (b - nz - 256) * 256 + t;     // head fp32 pack: [Wn | Wr | bn | br | Wc | bc]
    int s0 = IN * 128, s1 = s0 + 128 * 128, s2 = s1 + 128, s3 = s2 + 128, s4 = s3 + 256, s5 = s4 + 1;
    if (i >= s5) return;
    float v;
    if (i < s0) v = ldf(Wn, i, dt);
    else if (i < s1) v = ldf(Wr, i - s0, dt);
    else if (i < s2) v = ldf(bn, i - s1, dt);
    else if (i < s3) v = ldf(br, i - s2, dt);
    else if (i < s4) v = ldf(Wc, i - s3, dt);
    else v = ldf(bc, 0, dt);
    HW[i] = v;
  } else {
    int dt = block_detect(x, ndet);       // global flag for later dispatches
    if (t == 0) flag[0] = dt;
  }
}

// ---------------- CSR build ----------------
__global__ void count_rank(const int* __restrict__ ei, int E,
                           int* __restrict__ cnt, int* __restrict__ rank) {
  int e = blockIdx.x * blockDim.x + threadIdx.x;
  if (e >= E) return;
  int d = ei[E + e];
  rank[e] = atomicAdd(&cnt[d], 1);
}

// per-1024-chunk sums (round-1 proven). csum[b] = sum of cnt in chunk b.
__global__ __launch_bounds__(256) void scan_reduce(const int* __restrict__ cnt, int n, int* __restrict__ csum) {
  int base = blockIdx.x * 1024;
  int t = threadIdx.x;
  int s = 0;
#pragma unroll
  for (int j = 0; j < 4; j++) {
    int i = base + t * 4 + j;
    if (i < n) s += cnt[i];
  }
#pragma unroll
  for (int off = 32; off > 0; off >>= 1) s += __shfl_down(s, off, 64);
  __shared__ int ws[4];
  if ((t & 63) == 0) ws[t >> 6] = s;
  __syncthreads();
  if (t == 0) csum[blockIdx.x] = ws[0] + ws[1] + ws[2] + ws[3];
}

// scan_down2: folds the old scan_top into scan_down. Wave 0 of every block computes
// its own csum-prefix (nb<=~64 chunk sums, loop-strided + shuffle reduce) -- replaces
// the single-block scan_top dispatch. Round-8 lesson: never give one block 50K elements
// (scan_block: 77us at 0.05% BW); this keeps the proven 49-block parallel structure.
__global__ __launch_bounds__(256) void scan_down2(const int* __restrict__ cnt, int n,
                                                  const int* __restrict__ csum,
                                                  int* __restrict__ rowstart, int nb) {
  __shared__ int sbase;
  __shared__ int ws[4];
  int t = threadIdx.x, lane = t & 63, w = t >> 6;
  if (t < 64) {
    int vb = 0, vt = 0;
    for (int i = t; i < nb; i += 64) {
      int c = csum[i];
      vt += c;
      if (i < (int)blockIdx.x) vb += c;
    }
#pragma unroll
    for (int off = 32; off > 0; off >>= 1) {
      vb += __shfl_down(vb, off, 64);
      vt += __shfl_down(vt, off, 64);
    }
    if (t == 0) {
      sbase = vb;
      if (blockIdx.x == 0) rowstart[n] = vt;   // total (written once)
    }
  }
  int base = blockIdx.x * 1024;
  int v[4];
#pragma unroll
  for (int j = 0; j < 4; j++) {
    int i = base + t * 4 + j;
    v[j] = (i < n) ? cnt[i] : 0;
  }
  int s1 = v[0], s2 = s1 + v[1], s3 = s2 + v[2], s4 = s3 + v[3];
  int x = s4;
#pragma unroll
  for (int off = 1; off < 64; off <<= 1) {
    int y = __shfl_up(x, off, 64);
    if (lane >= off) x += y;
  }
  int texcl = x - s4;
  if (lane == 63) ws[w] = x;
  __syncthreads();
  int woff = 0;
  for (int i = 0; i < 4; i++) if (i < w) woff += ws[i];
  int b0 = sbase + woff + texcl;
  int e0 = b0, e1 = b0 + s1, e2 = b0 + s2, e3 = b0 + s3;
  int i0 = base + t * 4;
  if (i0 + 0 < n) rowstart[i0 + 0] = e0;
  if (i0 + 1 < n) rowstart[i0 + 1] = e1;
  if (i0 + 2 < n) rowstart[i0 + 2] = e2;
  if (i0 + 3 < n) rowstart[i0 + 3] = e3;
}

__global__ void scatter2(const int* __restrict__ ei, int E,
                         const int* __restrict__ rowstart, const int* __restrict__ rank,
                         int* __restrict__ adj) {
  int e = blockIdx.x * blockDim.x + threadIdx.x;
  if (e >= E) return;
  int s = ei[e], d = ei[E + e];
  adj[rowstart[d] + rank[e]] = s;
}

// ---------------- MFMA GEMM v4: LDS A-panel, fused fp32->bf16 staging ----------------
template <int RB, bool ALIGN16, bool CVT>
__global__ __launch_bounds__(256) void mfma_gemm4(const void* __restrict__ A0,
                                                  const ushort* __restrict__ Wt2,
                                                  bf16* __restrict__ C,
                                                  float2* __restrict__ as2, float2* __restrict__ ad2,
                                                  const void* __restrict__ aS, const void* __restrict__ aD,
                                                  int nrows, int K, const int* __restrict__ dtflag) {
  __shared__ __align__(16) unsigned char panel[64 * RB + 64];  // +64 pad (zeroed) for tail reads
  int dtg = dtflag[0];
  int tid = threadIdx.x;
  int row0 = blockIdx.x * 64;

  if (CVT && dtg) {
    const float* Af = (const float*)A0 + (size_t)row0 * K;
    size_t availf = (size_t)nrows * K - (size_t)row0 * K;
    size_t pf = availf < (size_t)(64 * K) ? availf : (size_t)(64 * K);
    int nch = (int)(pf >> 2);
    for (int c = tid; c < nch; c += 256) {
      float4 v = ((const float4*)Af)[c];
      uint2 o;
      o.x = (uint)toBF(v.x) | ((uint)toBF(v.y) << 16);
      o.y = (uint)toBF(v.z) | ((uint)toBF(v.w) << 16);
      *(uint2*)&panel[(size_t)c << 3] = o;
    }
    for (int f = (nch << 2) + tid; f < (int)pf; f += 256)
      ((ushort*)panel)[f] = toBF(Af[f]);
    for (int u2 = (int)pf + tid; u2 < (64 * RB + 64) / 2; u2 += 256)
      ((ushort*)panel)[u2] = 0;
  } else {
    const unsigned char* A = (const unsigned char*)A0;
    size_t gbase = (size_t)row0 * RB;
    size_t avail = (size_t)nrows * RB - gbase;
    size_t pbytes = avail < (size_t)(64 * RB) ? avail : (size_t)(64 * RB);
    int nchunk = (int)(pbytes >> 4);
    const uint4* gsrc = (const uint4*)(A + gbase);
    for (int c = tid; c < nchunk; c += 256)
      *(uint4*)&panel[(size_t)c << 4] = gsrc[c];
    for (int b = (nchunk << 4) + tid * 4; b < (int)pbytes; b += 1024)
      *(uint*)&panel[b] = *(const uint*)(A + gbase + b);
    for (int b = (int)((pbytes + 3) & ~3ull) + tid * 4; b < 64 * RB + 64; b += 1024)
      *(uint*)&panel[b] = 0u;
  }
  __syncthreads();

  int wave = tid >> 6, lane = tid & 63;
  int m = lane & 15, q = lane >> 4;
  int lrow = wave * 16 + m;
  const unsigned char* prow = &panel[(size_t)lrow * RB];

  f32x4 acc[8];
#pragma unroll
  for (int ct = 0; ct < 8; ct++) acc[ct] = (f32x4){0.f, 0.f, 0.f, 0.f};

  const ushort* wq = Wt2 + (size_t)q * 1024 + (size_t)m * 8;
  int niter = (K + 31) >> 5;
  for (int it = 0; it < niter; it++) {
    bf16x8 av;
    if (ALIGN16) {
      av = *(const bf16x8*)(prow + it * 64 + q * 16);
    } else {
      uint u[4];
#pragma unroll
      for (int j = 0; j < 4; j++) u[j] = *(const uint*)(prow + it * 64 + q * 16 + j * 4);
      __builtin_memcpy(&av, u, 16);
    }
    const ushort* wk = wq + (size_t)it * 4096;
    bf16x8 wv[8];
#pragma unroll
    for (int ct = 0; ct < 8; ct++) wv[ct] = *(const bf16x8*)(wk + ct * 128);
#pragma unroll
    for (int ct = 0; ct < 8; ct++)
      acc[ct] = __builtin_amdgcn_mfma_f32_16x16x32_bf16(av, wv[ct], acc[ct], 0, 0, 0);
  }

  // ---- C writeback (C/D: col=lane&15, row=q*4+r) ----
#pragma unroll
  for (int ct = 0; ct < 8; ct++) {
#pragma unroll
    for (int r = 0; r < 4; r++) {
      int grow = row0 + wave * 16 + q * 4 + r;
      if (grow < nrows) C[(size_t)grow * 128 + ct * 16 + m] = __float2bfloat16(acc[ct][r]);
    }
  }

  // ---- fused attention logits ----
  float aSv[8], aDv[8];
#pragma unroll
  for (int ct = 0; ct < 8; ct++) {
    aSv[ct] = ldf(aS, ct * 16 + m, dtg);
    aDv[ct] = ldf(aD, ct * 16 + m, dtg);
  }
#pragma unroll
  for (int r = 0; r < 4; r++) {
    float s0 = 0.f, s1 = 0.f, d0 = 0.f, d1 = 0.f;
#pragma unroll
    for (int ct = 0; ct < 4; ct++) {
      float v = acc[ct][r];
      s0 += v * aSv[ct]; d0 += v * aDv[ct];
    }
#pragma unroll
    for (int ct = 4; ct < 8; ct++) {
      float v = acc[ct][r];
      s1 += v * aSv[ct]; d1 += v * aDv[ct];
    }
#pragma unroll
    for (int off = 1; off < 16; off <<= 1) {
      s0 += __shfl_xor(s0, off, 64);
      s1 += __shfl_xor(s1, off, 64);
      d0 += __shfl_xor(d0, off, 64);
      d1 += __shfl_xor(d1, off, 64);
    }
    int grow = row0 + wave * 16 + q * 4 + r;
    if (m == 0 && grow < nrows) {
      as2[grow] = make_float2(s0, s1);
      ad2[grow] = make_float2(d0, d1);
    }
  }
}

// ---------------- generic fallback GEMM (any K / dtype) -------
__global__ __launch_bounds__(256) void mfma_gemm_gen(const void* __restrict__ A, const ushort* __restrict__ Wt2,
                                                     bf16* __restrict__ C,
                                                     float2* __restrict__ as2, float2* __restrict__ ad2,
                                                     const void* __restrict__ aS, const void* __restrict__ aD,
                                                     int nrows, int K, const int* __restrict__ dtflag) {
  int dtg = dtflag[0];
  int tid = threadIdx.x;
  int wave = tid >> 6, lane = tid & 63;
  int m = lane & 15, q = lane >> 4;
  int row0 = blockIdx.x * 64;
  int rowA = row0 + wave * 16 + m;
  int rA = rowA < nrows ? rowA : nrows - 1;

  f32x4 acc[8];
#pragma unroll
  for (int ct = 0; ct < 8; ct++) acc[ct] = (f32x4){0.f, 0.f, 0.f, 0.f};

  const ushort* wq = Wt2 + (size_t)q * 1024 + (size_t)m * 8;
  int niter = (K + 31) >> 5;
  for (int it = 0; it < niter; it++) {
    ushort u[8];
#pragma unroll
    for (int j = 0; j < 8; j++) {
      int k = it * 32 + q * 8 + j;
      u[j] = (k < K) ? toBF(ldf(A, (size_t)rA * K + k, dtg)) : (ushort)0;
    }
    bf16x8 av;
    __builtin_memcpy(&av, u, 16);
    const ushort* wk = wq + (size_t)it * 4096;
    bf16x8 wv[8];
#pragma unroll
    for (int ct = 0; ct < 8; ct++) wv[ct] = *(const bf16x8*)(wk + ct * 128);
#pragma unroll
    for (int ct = 0; ct < 8; ct++)
      acc[ct] = __builtin_amdgcn_mfma_f32_16x16x32_bf16(av, wv[ct], acc[ct], 0, 0, 0);
  }
#pragma unroll
  for (int ct = 0; ct < 8; ct++) {
#pragma unroll
    for (int r = 0; r < 4; r++) {
      int grow = row0 + wave * 16 + q * 4 + r;
      if (grow < nrows) C[(size_t)grow * 128 + ct * 16 + m] = __float2bfloat16(acc[ct][r]);
    }
  }
  float aSv[8], aDv[8];
#pragma unroll
  for (int ct = 0; ct < 8; ct++) {
    aSv[ct] = ldf(aS, ct * 16 + m, dtg);
    aDv[ct] = ldf(aD, ct * 16 + m, dtg);
  }
#pragma unroll
  for (int r = 0; r < 4; r++) {
    float s0 = 0.f, s1 = 0.f, d0 = 0.f, d1 = 0.f;
#pragma unroll
    for (int ct = 0; ct < 4; ct++) { float v = acc[ct][r]; s0 += v * aSv[ct]; d0 += v * aDv[ct]; }
#pragma unroll
    for (int ct = 4; ct < 8; ct++) { float v = acc[ct][r]; s1 += v * aSv[ct]; d1 += v * aDv[ct]; }
#pragma unroll
    for (int off = 1; off < 16; off <<= 1) {
      s0 += __shfl_xor(s0, off, 64);
      s1 += __shfl_xor(s1, off, 64);
      d0 += __shfl_xor(d0, off, 64);
      d1 += __shfl_xor(d1, off, 64);
    }
    int grow = row0 + wave * 16 + q * 4 + r;
    if (m == 0 && grow < nrows) {
      as2[grow] = make_float2(s0, s1);
      ad2[grow] = make_float2(d0, d1);
    }
  }
}

// ---------------- GAT aggregate, write epilogue (round-1 proven structure) ----------
#define GCAP 64
__global__ __launch_bounds__(256) void gat_agg7w(const bf16* __restrict__ xw,
                                                 const float2* __restrict__ as2, const float2* __restrict__ ad2,
                                                 const int* __restrict__ rowstart, const int* __restrict__ adj,
                                                 const void* __restrict__ bias, bf16* __restrict__ out, int N,
                                                 const int* __restrict__ dtflag) {
  __shared__ float2 sW[4][GCAP];
  __shared__ int sS[4][GCAP];
  int dt = dtflag[0];
  int wslot = threadIdx.x >> 6;
  int lane = threadIdx.x & 63;
  int n = (blockIdx.x * blockDim.x + threadIdx.x) >> 6;
  bool act = n < N;
  int r0 = 0, r1 = 0;
  float2 adv = make_float2(0.f, 0.f), asn = make_float2(0.f, 0.f);
  if (act) { r0 = rowstart[n]; r1 = rowstart[n + 1]; adv = ad2[n]; asn = as2[n]; }
  int deg = r1 - r0;

  float es0 = asn.x + adv.x; es0 = es0 > 0.f ? es0 : 0.2f * es0;
  float es1 = asn.y + adv.y; es1 = es1 > 0.f ? es1 : 0.2f * es1;
  float ws0 = __expf(fminf(es0, 60.f)), ws1 = __expf(fminf(es1, 60.f));

  float den0, den1;
  {
    bool v = act && lane < deg;
    int s = v ? adj[r0 + lane] : 0;
    float w0 = 0.f, w1 = 0.f;
    if (v) {
      float2 asv = as2[s];
      float e0 = asv.x + adv.x; e0 = e0 > 0.f ? e0 : 0.2f * e0;
      float e1 = asv.y + adv.y; e1 = e1 > 0.f ? e1 : 0.2f * e1;
      w0 = __expf(fminf(e0, 60.f)); w1 = __expf(fminf(e1, 60.f));
    }
    sW[wslot][lane] = make_float2(w0, w1);
    sS[wslot][lane] = s;
    den0 = w0; den1 = w1;
  }
  for (int i = r0 + GCAP + lane; i < r1; i += 64) {
    int s = adj[i];
    float2 asv = as2[s];
    float e0 = asv.x + adv.x; e0 = e0 > 0.f ? e0 : 0.2f * e0;
    float e1 = asv.y + adv.y; e1 = e1 > 0.f ? e1 : 0.2f * e1;
    den0 += __expf(fminf(e0, 60.f)); den1 += __expf(fminf(e1, 60.f));
  }
#pragma unroll
  for (int off = 32; off > 0; off >>= 1) {
    den0 += __shfl_xor(den0, off, 64);
    den1 += __shfl_xor(den1, off, 64);
  }
  den0 += ws0; den1 += ws1;
  float inv0 = 1.f / (den0 + 1e-16f), inv1 = 1.f / (den1 + 1e-16f);

  const uint* xw32 = (const uint*)xw;
  float wsS = (lane < 32) ? ws0 : ws1;
  uint pvs = act ? xw32[((size_t)n << 6) + lane] : 0;
  float a0 = wsS * __uint_as_float(pvs << 16);
  float a1 = wsS * __uint_as_float(pvs & 0xffff0000u);
  int cap = deg < GCAP ? deg : GCAP;
  int capR = (cap + 7) & ~7;   // wave-uniform; slots [cap,capR) have w=0,s=0
  for (int i = 0; i < capR; i += 8) {
    uint pv[8]; float wsv[8];
#pragma unroll
    for (int j = 0; j < 8; j++) {
      float2 wv = sW[wslot][i + j];
      int s = sS[wslot][i + j];
      wsv[j] = (lane < 32) ? wv.x : wv.y;
      pv[j] = xw32[((size_t)s << 6) + lane];
    }
#pragma unroll
    for (int j = 0; j < 8; j++) {
      a0 += wsv[j] * __uint_as_float(pv[j] << 16);
      a1 += wsv[j] * __uint_as_float(pv[j] & 0xffff0000u);
    }
  }
  for (int i = GCAP; i < deg; i++) {
    int s = adj[r0 + i];
    float2 asv = as2[s];
    float e0 = asv.x + adv.x; e0 = e0 > 0.f ? e0 : 0.2f * e0;
    float e1 = asv.y + adv.y; e1 = e1 > 0.f ? e1 : 0.2f * e1;
    float w0 = __expf(fminf(e0, 60.f)), w1 = __expf(fminf(e1, 60.f));
    uint pv = xw32[((size_t)s << 6) + lane];
    float ws = (lane < 32) ? w0 : w1;
    a0 += ws * __uint_as_float(pv << 16);
    a1 += ws * __uint_as_float(pv & 0xffff0000u);
  }
  if (act) {
    int c0 = 2 * lane;
    float invs = (lane < 32) ? inv0 : inv1;
    float o0 = a0 * invs + ldf(bias, c0, dt);
    float o1 = a1 * invs + ldf(bias, c0 + 1, dt);
    o0 = o0 > 0.f ? o0 : 0.f;
    o1 = o1 > 0.f ? o1 : 0.f;
    uint pk = (uint)toBF(o0) | ((uint)toBF(o1) << 16);
    ((uint*)out)[(size_t)n * 64 + lane] = pk;
  }
}

// ---------------- head v5: mean-pool fused in (no pool dispatch, no atomics) ----------
__global__ __launch_bounds__(512) void head5_kernel(
    const bf16* __restrict__ h, const void* __restrict__ x, const int* __restrict__ batch,
    const float* __restrict__ HW, void* __restrict__ out, int N, int IN,
    const int* __restrict__ dtflag) {
  const float* Wn_f = HW;
  const float* Wr_f = HW + (size_t)IN * 128;
  const float* bn_f = Wr_f + 128 * 128;
  const float* br_f = bn_f + 128;
  const float* Wc_f = br_f + 128;
  const float* bc_f = Wc_f + 256;
  int dt = dtflag[0];
  int b = blockIdx.x;
  int tid = threadIdx.x;
  int t = tid & 127, g = tid >> 7;
  __shared__ int sr0, sr1;
  __shared__ float xs[512];
  __shared__ float pl[128];
  __shared__ float pn[4][128];
  __shared__ float pg[4][128];
  __shared__ float red[128];
  if (tid == 0) {
    int lo = 0, hi = N;
    while (lo < hi) { int mid = (lo + hi) >> 1; if (batch[mid] < b) lo = mid + 1; else hi = mid; }
    sr0 = lo;
  }
  if (tid == 1) {
    int lo = 0, hi = N, b1 = b + 1;
    while (lo < hi) { int mid = (lo + hi) >> 1; if (batch[mid] < b1) lo = mid + 1; else hi = mid; }
    sr1 = lo;
  }
  __syncthreads();
  int r0 = sr0, r1 = sr1;
  float inv_cnt = 1.f / (float)(r1 - r0);
  if (dt) {
    const float* xf = (const float*)x + (size_t)r0 * IN;
    for (int k = tid; k < IN; k += 512) xs[k] = xf[k];
  } else {
    const bf16* xb = (const bf16*)x + (size_t)r0 * IN;
    for (int k = tid; k < IN; k += 512) xs[k] = toF(xb[k]);
  }
  // inline mean-pool over this graph's h rows (pn as scratch)
  float ap = 0.f;
  for (int nr = r0 + g; nr < r1; nr += 4)
    ap += toF(h[(size_t)nr * 128 + t]);
  pn[g][t] = ap;
  __syncthreads();
  if (tid < 128) pl[tid] = (pn[0][tid] + pn[1][tid] + pn[2][tid] + pn[3][tid]) * inv_cnt;
  __syncthreads();

  float n0 = 0.f, n1 = 0.f, n2 = 0.f, n3 = 0.f;
  {
    int k = g;
    for (; k + 12 < IN; k += 16) {
      n0 += xs[k]      * Wn_f[(size_t)k * 128 + t];
      n1 += xs[k + 4]  * Wn_f[(size_t)(k + 4) * 128 + t];
      n2 += xs[k + 8]  * Wn_f[(size_t)(k + 8) * 128 + t];
      n3 += xs[k + 12] * Wn_f[(size_t)(k + 12) * 128 + t];
    }
    for (; k < IN; k += 4) n0 += xs[k] * Wn_f[(size_t)k * 128 + t];
  }
  float g0 = 0.f, g1 = 0.f;
  {
    int k = g;
    for (; k + 4 < 128; k += 8) {
      g0 += pl[k]     * Wr_f[(size_t)k * 128 + t];
      g1 += pl[k + 4] * Wr_f[(size_t)(k + 4) * 128 + t];
    }
    for (; k < 128; k += 4) g0 += pl[k] * Wr_f[(size_t)k * 128 + t];
  }
  pn[g][t] = (n0 + n1) + (n2 + n3);
  pg[g][t] = g0 + g1;
  __syncthreads();
  if (tid < 128) {
    float nw = pn[0][t] + pn[1][t] + pn[2][t] + pn[3][t] + bn_f[t];
    nw = nw > 0.f ? nw : 0.f;
    float gg = pg[0][t] + pg[1][t] + pg[2][t] + pg[3][t] + br_f[t];
    gg = gg > 0.f ? gg : 0.f;
    red[t] = gg * Wc_f[t] + nw * Wc_f[128 + t];
  }
  __syncthreads();
  for (int s = 64; s > 0; s >>= 1) {
    if (tid < s) red[tid] += red[tid + s];
    __syncthreads();
  }
  if (tid == 0) {
    float z = red[0] + bc_f[0];
    float r = 1.f / (1.f + __expf(-z));
    if (dt) ((float*)out)[b] = r;
    else ((bf16*)out)[b] = __float2bfloat16(r);
  }
}

extern "C" void kernel_launch(void* const* d_in, const int* in_sizes, int n_in,
                              void* d_out, int out_size, void* d_ws, size_t ws_size,
                              hipStream_t stream) {
  const void* x   = d_in[0];
  const void* W0  = d_in[1];
  const void* aS0 = d_in[2];
  const void* aD0 = d_in[3];
  const void* b0  = d_in[4];
  const void* W1  = d_in[5];
  const void* aS1 = d_in[6];
  const void* aD1 = d_in[7];
  const void* b1  = d_in[8];
  const void* Wn  = d_in[9];
  const void* bn  = d_in[10];
  const void* Wr  = d_in[11];
  const void* br  = d_in[12];
  const void* Wc  = d_in[13];
  const void* bc  = d_in[14];
  const int* ei    = (const int*)d_in[15];
  const int* batch = (const int*)d_in[16];

  const int N = in_sizes[16];
  const int IN = in_sizes[0] / N;
  const int E = in_sizes[15] / 2;
  const int B = out_size;
  const int Kpad0 = (IN + 31) / 32 * 32;   // 320
  const int hw_elems = IN * 128 + 128 * 128 + 128 + 128 + 256 + 1;

  char* w = (char*)d_ws;
  size_t off = 0;
  auto alloc = [&](size_t bytes) { void* p = w + off; off += (bytes + 255) / 256 * 256; return p; };
  int* flag      = (int*)alloc(256);
  bf16* bufA     = (bf16*)alloc((size_t)N * 128 * 2);
  bf16* bufB     = (bf16*)alloc((size_t)N * 128 * 2);
  float2* as2    = (float2*)alloc((size_t)N * 8);
  float2* ad2    = (float2*)alloc((size_t)N * 8);
  int* cnt       = (int*)alloc((size_t)N * 4);
  int* rowstart  = (int*)alloc((size_t)(N + 1) * 4);
  int* rank      = (int*)alloc((size_t)E * 4);
  int* adj       = (int*)alloc((size_t)E * 4);
  int* csum      = (int*)alloc(1024);
  ushort* Wt0    = (ushort*)alloc((size_t)128 * Kpad0 * 2);
  ushort* Wt1    = (ushort*)alloc((size_t)128 * 128 * 2);
  float* HW      = (float*)alloc((size_t)hw_elems * 4);

  int ndet = in_sizes[0] < 4096 ? in_sizes[0] : 4096;
  int nz = (N + 255) / 256;
  int hb = (hw_elems + 255) / 256;
  int fgrid = nz + 256 + hb + 1;

  // dispatch 1: zero cnt + pack Wt0/Wt1/HW (self-detect) + write dtype flag
  fused_init_pack<<<fgrid, 256, 0, stream>>>(x, ndet, flag, cnt, N,
                                             W0, W1, Wn, Wr, bn, br, Wc, bc,
                                             Wt0, Wt1, HW, IN, Kpad0, nz, hb);

  // dispatches 2-5: CSR build (count -> parallel 2-dispatch scan -> scatter)
  const int tb = 256;
  count_rank<<<(E + tb - 1) / tb, tb, 0, stream>>>(ei, E, cnt, rank);
  int nb = (N + 1023) / 1024;
  scan_reduce<<<nb, 256, 0, stream>>>(cnt, N, csum);
  scan_down2<<<nb, 256, 0, stream>>>(cnt, N, csum, rowstart, nb);
  scatter2<<<(E + tb - 1) / tb, tb, 0, stream>>>(ei, E, rowstart, rank, adj);

  int ggrid = (N + 63) / 64;
  int wgrid = ((N * 64) + 255) / 256;

  // dispatches 6-9: layer 0 (GEMM + aggregate), layer 1 (GEMM + aggregate)
  if (IN == 310) {
    mfma_gemm4<620, false, true><<<ggrid, 256, 0, stream>>>(x, Wt0, bufA, as2, ad2, aS0, aD0, N, IN, flag);
  } else {
    mfma_gemm_gen<<<ggrid, 256, 0, stream>>>(x, Wt0, bufA, as2, ad2, aS0, aD0, N, IN, flag);
  }
  gat_agg7w<<<wgrid, 256, 0, stream>>>(bufA, as2, ad2, rowstart, adj, b0, bufB, N, flag);

  mfma_gemm4<256, true, false><<<ggrid, 256, 0, stream>>>(bufB, Wt1, bufA, as2, ad2, aS1, aD1, N, 128, flag);
  gat_agg7w<<<wgrid, 256, 0, stream>>>(bufA, as2, ad2, rowstart, adj, b1, bufB, N, flag);

  // dispatch 10: head with fused mean-pool
  head5_kernel<<<B, 512, 0, stream>>>(bufB, x, batch, HW, (void*)d_out, N, IN, flag);
}